// Round 15
// baseline (128.774 us; speedup 1.0000x reference)
//
#include <hip/hip_runtime.h>
#include <math.h>

#define FIN 128
#define H 64
#define FOUT 2
#define NEG_SLOPE 0.2f
#define EPS 1e-16f

#define SCAN_CHUNK 2048   // elements per scan_a block (256 thr * 8)

typedef __attribute__((ext_vector_type(8))) short s8v;   // 8 bf16 (4 VGPR)
typedef __attribute__((ext_vector_type(4))) float f4v;   // MFMA acc

// Preamble: exclusive scan of blocksum[0..nscan) into LDS bs[] (nscan <= 64).
__device__ __forceinline__ void load_bs(const int* __restrict__ blocksum, int nscan,
                                        int* bs, int tid){
  if(tid < 64){
    int v = (tid < nscan)? blocksum[tid] : 0;
    int incl = v;
    #pragma unroll
    for(int o=1;o<64;o<<=1){ int u=__shfl_up(incl,o); if(tid>=o) incl+=u; }
    bs[tid] = incl - v;
  }
  __syncthreads();
}

// K0: fused [zero deg] + [pack W into MFMA fragments, split hi/lo bf16].
// pW[((ct*4+k0)*64 + lane)*8 + j] = W_all[k0*32 + (lane>>4)*8 + j][ct*16 + (lane&15)]
// As the A-operand this is (W^T)[row=lane&15][k] — exactly the A-frag for D = W^T x.
__global__ void k_prep(int* __restrict__ deg, int N, int ZB,
                       const float* __restrict__ Wl, const float* __restrict__ Wr,
                       unsigned short* __restrict__ pWh, unsigned short* __restrict__ pWe){
  int b = blockIdx.x;
  if(b < ZB){
    int i = b*256 + threadIdx.x;
    if(i < N) deg[i] = 0;
    return;
  }
  int idx = (b - ZB)*256 + threadIdx.x;     // (ct*4+k0)*64 + lane, < 2048
  int lane = idx & 63;
  int ctk  = idx >> 6;
  int k0   = (ctk & 3) * 32;
  int ct   = ctk >> 2;
  int c    = ct*16 + (lane & 15);
  int kb   = k0 + (lane >> 4)*8;
  const float* Wp = (c < 64) ? (Wl + c) : (Wr + (c - 64));
  #pragma unroll
  for(int j=0;j<8;j++){
    float v = Wp[(size_t)(kb + j)*H];
    unsigned u = __float_as_uint(v);
    unsigned short hb = (unsigned short)(u >> 16);
    float hv = __uint_as_float(((unsigned)hb) << 16);
    float ev = v - hv;
    unsigned short eb = (unsigned short)(__float_as_uint(ev) >> 16);
    pWh[(size_t)idx*8 + j] = hb;
    pWe[(size_t)idx*8 + j] = eb;
  }
}

// K1: MFMA GEMM, SWAPPED operands: D = W^T x  (A = packed W, B = x fragments).
// C/D map (col=lane&15 -> x-row, row=(lane>>4)*4+reg -> weight col) means each
// lane owns 4 CONSECUTIVE weight cols of one row -> float4 / ushort4 stores
// (no 4B scatter, no partial-line RMW).  xl fp32 is dead -> only xlb (bf16) + xr.
__global__ __launch_bounds__(256) void k_gemm_mfma(
    const float* __restrict__ x,
    const unsigned short* __restrict__ pWh, const unsigned short* __restrict__ pWe,
    float* __restrict__ xr, unsigned short* __restrict__ xlb, int N){
  int tid = threadIdx.x;
  int lane = tid & 63, wid = tid >> 6;
  int rowbase = blockIdx.x*64 + wid*16;
  int r = lane & 15, g = lane >> 4;

  int arow = rowbase + r; if(arow > N-1) arow = N-1;   // clamp for load
  const float* xrow = x + (size_t)arow*FIN;
  int orow = rowbase + r;                               // guard for store

  // x B-fragments for 4 k-steps, hi/lo split: B[k][n]: n = lane&15 (x-row),
  // k = (lane>>4)*8+j  -> lane loads x[arow][k0*32 + g*8 + j]  (same gather as before)
  s8v xh[4], xe[4];
  #pragma unroll
  for(int k0=0;k0<4;k0++){
    float4 va = *(const float4*)(xrow + k0*32 + g*8);
    float4 vb = *(const float4*)(xrow + k0*32 + g*8 + 4);
    float xs_[8] = {va.x,va.y,va.z,va.w,vb.x,vb.y,vb.z,vb.w};
    #pragma unroll
    for(int j=0;j<8;j++){
      unsigned u = __float_as_uint(xs_[j]);
      unsigned short hb = (unsigned short)(u >> 16);
      xh[k0][j] = (short)hb;
      float ev = xs_[j] - __uint_as_float(((unsigned)hb) << 16);
      xe[k0][j] = (short)(unsigned short)(__float_as_uint(ev) >> 16);
    }
  }

  #pragma unroll 2
  for(int ct=0;ct<8;ct++){
    f4v a = (f4v){0.f,0.f,0.f,0.f};
    #pragma unroll
    for(int k0=0;k0<4;k0++){
      size_t boff = ((size_t)(ct*4 + k0)*64 + lane)*8;
      s8v wh = *(const s8v*)(pWh + boff);
      s8v we = *(const s8v*)(pWe + boff);
      a = __builtin_amdgcn_mfma_f32_16x16x32_bf16(wh, xh[k0], a, 0,0,0);
      a = __builtin_amdgcn_mfma_f32_16x16x32_bf16(wh, xe[k0], a, 0,0,0);
      a = __builtin_amdgcn_mfma_f32_16x16x32_bf16(we, xh[k0], a, 0,0,0);
    }
    if(orow < N){
      if(ct < 4){
        // Wl cols ct*16 + g*4 .. +3  ->  xlb (bf16, RNE), one 8B store
        ushort4 pk;
        unsigned u0 = __float_as_uint(a[0]);
        unsigned u1 = __float_as_uint(a[1]);
        unsigned u2 = __float_as_uint(a[2]);
        unsigned u3 = __float_as_uint(a[3]);
        pk.x = (unsigned short)((u0 + 0x7FFF + ((u0>>16)&1)) >> 16);
        pk.y = (unsigned short)((u1 + 0x7FFF + ((u1>>16)&1)) >> 16);
        pk.z = (unsigned short)((u2 + 0x7FFF + ((u2>>16)&1)) >> 16);
        pk.w = (unsigned short)((u3 + 0x7FFF + ((u3>>16)&1)) >> 16);
        *(ushort4*)(xlb + (size_t)orow*H + ct*16 + g*4) = pk;
      } else {
        // Wr cols (ct-4)*16 + g*4 .. +3 -> xr fp32, one float4 store
        *(float4*)(xr + (size_t)orow*H + (ct-4)*16 + g*4) =
            make_float4(a[0],a[1],a[2],a[3]);
      }
    }
  }
}

// K2: degree count + per-edge rank, 8 edges/thread (standalone — fusion twice
// measured = serial sum of parts; separate keeps profiler visibility)
__global__ void k_degree(const int* __restrict__ ei, int E, int Etot,
                         int* __restrict__ deg, int* __restrict__ rank){
  int i0 = (blockIdx.x*blockDim.x + threadIdx.x)*8;
  if(i0 >= Etot) return;
  if(i0 + 8 <= E && (E & 3) == 0){
    int4 da = *(const int4*)(ei + E + i0);
    int4 db = *(const int4*)(ei + E + i0 + 4);
    int r0 = atomicAdd(&deg[da.x],1);
    int r1 = atomicAdd(&deg[da.y],1);
    int r2 = atomicAdd(&deg[da.z],1);
    int r3 = atomicAdd(&deg[da.w],1);
    int r4 = atomicAdd(&deg[db.x],1);
    int r5 = atomicAdd(&deg[db.y],1);
    int r6 = atomicAdd(&deg[db.z],1);
    int r7 = atomicAdd(&deg[db.w],1);
    *(int4*)(rank + i0)     = make_int4(r0,r1,r2,r3);
    *(int4*)(rank + i0 + 4) = make_int4(r4,r5,r6,r7);
  } else if(i0 >= E && i0 + 8 <= Etot){
    int v = i0 - E;
    int r0 = atomicAdd(&deg[v+0],1);
    int r1 = atomicAdd(&deg[v+1],1);
    int r2 = atomicAdd(&deg[v+2],1);
    int r3 = atomicAdd(&deg[v+3],1);
    int r4 = atomicAdd(&deg[v+4],1);
    int r5 = atomicAdd(&deg[v+5],1);
    int r6 = atomicAdd(&deg[v+6],1);
    int r7 = atomicAdd(&deg[v+7],1);
    *(int4*)(rank + i0)     = make_int4(r0,r1,r2,r3);
    *(int4*)(rank + i0 + 4) = make_int4(r4,r5,r6,r7);
  } else {
    #pragma unroll
    for(int q=0;q<8;q++){
      int i = i0+q; if(i>=Etot) break;
      int dst = (i<E) ? ei[E+i] : (i-E);
      rank[i] = atomicAdd(&deg[dst],1);
    }
  }
}

// K3: per-block scan of deg, LOCAL-exclusive into rowptr + block totals.
__global__ __launch_bounds__(256) void k_scan_a(const int* __restrict__ deg, int n,
                                                int* __restrict__ rowptr,
                                                int* __restrict__ blocksum){
  __shared__ int wsum[4];
  int tid = threadIdx.x, lane = tid & 63, wid = tid >> 6;
  int idx = blockIdx.x*SCAN_CHUNK + tid*8;
  int v[8];
  if(idx + 8 <= n){
    int4 a = *(const int4*)(deg + idx);
    int4 b = *(const int4*)(deg + idx + 4);
    v[0]=a.x;v[1]=a.y;v[2]=a.z;v[3]=a.w;v[4]=b.x;v[5]=b.y;v[6]=b.z;v[7]=b.w;
  } else {
    #pragma unroll
    for(int i=0;i<8;i++) v[i] = (idx+i<n)? deg[idx+i] : 0;
  }
  int pre[8]; int st=0;
  #pragma unroll
  for(int i=0;i<8;i++){ pre[i]=st; st+=v[i]; }
  int incl = st;
  #pragma unroll
  for(int o=1;o<64;o<<=1){ int u=__shfl_up(incl,o); if(lane>=o) incl+=u; }
  if(lane==63) wsum[wid]=incl;
  __syncthreads();
  if(tid==0){ int accu=0; for(int i=0;i<4;i++){ int t=wsum[i]; wsum[i]=accu; accu+=t; } }
  __syncthreads();
  int toff = wsum[wid] + incl - st;
  if(idx + 8 <= n){
    int4 o0 = make_int4(toff+pre[0],toff+pre[1],toff+pre[2],toff+pre[3]);
    int4 o1 = make_int4(toff+pre[4],toff+pre[5],toff+pre[6],toff+pre[7]);
    *(int4*)(rowptr+idx)=o0; *(int4*)(rowptr+idx+4)=o1;
  } else {
    #pragma unroll
    for(int i=0;i<8;i++) if(idx+i<n) rowptr[idx+i]=toff+pre[i];
  }
  if(tid==255){
    blocksum[blockIdx.x] = toff + st;
    if(blockIdx.x == gridDim.x-1) rowptr[n] = toff + st;
  }
}

// K4: CSR fill — no atomics; 8 edges/thread
__global__ void k_fill(const int* __restrict__ ei, int E, int Etot,
                       const int* __restrict__ rowptr,
                       const int* __restrict__ blocksum, int nscan,
                       const int* __restrict__ rank, int* __restrict__ csr_src){
  __shared__ int bs[64];
  int tid = threadIdx.x;
  load_bs(blocksum, nscan, bs, tid);
  int i0 = (blockIdx.x*blockDim.x + tid)*8;
  if(i0 >= Etot) return;
  if(i0 + 8 <= E && (E & 3) == 0){
    int4 sa = *(const int4*)(ei + i0);
    int4 sb = *(const int4*)(ei + i0 + 4);
    int4 da = *(const int4*)(ei + E + i0);
    int4 db = *(const int4*)(ei + E + i0 + 4);
    int4 ra = *(const int4*)(rank + i0);
    int4 rb = *(const int4*)(rank + i0 + 4);
    csr_src[rowptr[da.x] + bs[da.x>>11] + ra.x] = sa.x;
    csr_src[rowptr[da.y] + bs[da.y>>11] + ra.y] = sa.y;
    csr_src[rowptr[da.z] + bs[da.z>>11] + ra.z] = sa.z;
    csr_src[rowptr[da.w] + bs[da.w>>11] + ra.w] = sa.w;
    csr_src[rowptr[db.x] + bs[db.x>>11] + rb.x] = sb.x;
    csr_src[rowptr[db.y] + bs[db.y>>11] + rb.y] = sb.y;
    csr_src[rowptr[db.z] + bs[db.z>>11] + rb.z] = sb.z;
    csr_src[rowptr[db.w] + bs[db.w>>11] + rb.w] = sb.w;
  } else if(i0 >= E && i0 + 8 <= Etot){
    int4 ra = *(const int4*)(rank + i0);
    int4 rb = *(const int4*)(rank + i0 + 4);
    int v = i0 - E;
    csr_src[rowptr[v+0] + bs[(v+0)>>11] + ra.x] = v+0;
    csr_src[rowptr[v+1] + bs[(v+1)>>11] + ra.y] = v+1;
    csr_src[rowptr[v+2] + bs[(v+2)>>11] + ra.z] = v+2;
    csr_src[rowptr[v+3] + bs[(v+3)>>11] + ra.w] = v+3;
    csr_src[rowptr[v+4] + bs[(v+4)>>11] + rb.x] = v+4;
    csr_src[rowptr[v+5] + bs[(v+5)>>11] + rb.y] = v+5;
    csr_src[rowptr[v+6] + bs[(v+6)>>11] + rb.z] = v+6;
    csr_src[rowptr[v+7] + bs[(v+7)>>11] + rb.w] = v+7;
  } else {
    #pragma unroll
    for(int q=0;q<8;q++){
      int i = i0+q; if(i>=Etot) break;
      int src, dst;
      if(i<E){ src = ei[i]; dst = ei[E+i]; } else { src = i-E; dst = i-E; }
      csr_src[rowptr[dst] + bs[dst>>11] + rank[i]] = src;
    }
  }
}

// K5: fused layer-1 (no-max softmax).  32 lanes/node = 2 groups of 16.
__global__ void k_node1f(const int* __restrict__ rowptr, const int* __restrict__ blocksum,
                         int nscan, const int* __restrict__ csr_src,
                         const unsigned short* __restrict__ xlb, const float* __restrict__ xr,
                         const float* __restrict__ att, const float* __restrict__ b1,
                         const float* __restrict__ Wl2, const float* __restrict__ Wr2,
                         float* __restrict__ xl2, float* __restrict__ xr2, int N){
  __shared__ int bs[64];
  int tid = threadIdx.x;
  load_bs(blocksum, nscan, bs, tid);
  int node = blockIdx.x*8 + (tid>>5);
  int half = (tid >> 4) & 1;
  int gl = tid & 15;
  if(node >= N) return;
  int f4 = gl*4;
  float4 attv = *(const float4*)(att + f4);
  float4 xrv  = *(const float4*)(xr + (size_t)node*H + f4);
  int s = rowptr[node]   + bs[node>>11];
  int t = rowptr[node+1] + bs[(node+1)>>11];
  float d = 0.f;
  float ax=0.f, ay=0.f, az=0.f, aw=0.f;

  for(int k = s + half*8; k < t; k += 16){
    int tl = t - 1;
    int ks[8]; float4 xv[8]; float msk[8];
    #pragma unroll
    for(int j=0;j<8;j++){
      int kj = k + j;
      ks[j] = (kj < t) ? kj : tl;
      msk[j] = (kj < t) ? 1.f : 0.f;
    }
    int ss[8];
    #pragma unroll
    for(int j=0;j<8;j++) ss[j] = csr_src[ks[j]];
    #pragma unroll
    for(int j=0;j<8;j++){
      ushort4 uv = *(const ushort4*)(xlb + (size_t)ss[j]*H + f4);
      xv[j].x = __uint_as_float((unsigned)uv.x << 16);
      xv[j].y = __uint_as_float((unsigned)uv.y << 16);
      xv[j].z = __uint_as_float((unsigned)uv.z << 16);
      xv[j].w = __uint_as_float((unsigned)uv.w << 16);
    }
    #pragma unroll
    for(int j=0;j<8;j++){
      float h0 = xv[j].x + xrv.x, h1 = xv[j].y + xrv.y;
      float h2 = xv[j].z + xrv.z, h3 = xv[j].w + xrv.w;
      float l0 = (h0>0.f)? h0 : NEG_SLOPE*h0;
      float l1 = (h1>0.f)? h1 : NEG_SLOPE*h1;
      float l2 = (h2>0.f)? h2 : NEG_SLOPE*h2;
      float l3 = (h3>0.f)? h3 : NEG_SLOPE*h3;
      float e = l0*attv.x + l1*attv.y + l2*attv.z + l3*attv.w;
      #pragma unroll
      for(int o=1;o<16;o<<=1) e += __shfl_xor(e,o);
      float w = msk[j] * __expf(e);
      d  += w;
      ax += w*xv[j].x; ay += w*xv[j].y; az += w*xv[j].z; aw += w*xv[j].w;
    }
  }

  d  += __shfl_xor(d,16);
  ax += __shfl_xor(ax,16); ay += __shfl_xor(ay,16);
  az += __shfl_xor(az,16); aw += __shfl_xor(aw,16);

  float inv = 1.f/(d + EPS);
  float4 bv = *(const float4*)(b1 + f4);
  float h0 = ax*inv + bv.x, h1 = ay*inv + bv.y;
  float h2 = az*inv + bv.z, h3 = aw*inv + bv.w;
  const float* Wp = half ? Wr2 : Wl2;
  float pa = h0*Wp[(f4+0)*FOUT+0] + h1*Wp[(f4+1)*FOUT+0] + h2*Wp[(f4+2)*FOUT+0] + h3*Wp[(f4+3)*FOUT+0];
  float pb = h0*Wp[(f4+0)*FOUT+1] + h1*Wp[(f4+1)*FOUT+1] + h2*Wp[(f4+2)*FOUT+1] + h3*Wp[(f4+3)*FOUT+1];
  #pragma unroll
  for(int o=1;o<16;o<<=1){
    pa += __shfl_xor(pa,o); pb += __shfl_xor(pb,o);
  }
  if(gl==0){
    float2 pv = make_float2(pa,pb);
    if(half==0) *(float2*)(xl2 + node*2) = pv;
    else        *(float2*)(xr2 + node*2) = pv;
  }
}

// K6: layer-2 full conv, single pass (no-max), 16-lane group per node
__global__ void k_node2(const int* __restrict__ rowptr, const int* __restrict__ blocksum,
                        int nscan, const int* __restrict__ csr_src,
                        const float* __restrict__ xl2, const float* __restrict__ xr2,
                        const float* __restrict__ att2, const float* __restrict__ b2,
                        float* __restrict__ out, int N){
  __shared__ int bs[64];
  int tid = threadIdx.x;
  load_bs(blocksum, nscan, bs, tid);
  int node = blockIdx.x*16 + (tid>>4);
  int gl = tid & 15;
  if(node >= N) return;
  int s = rowptr[node]   + bs[node>>11];
  int t = rowptr[node+1] + bs[(node+1)>>11];
  float2 xrv = *(const float2*)(xr2 + node*2);
  float a0 = att2[0], a1 = att2[1];
  float den=0.f, n0=0.f, n1=0.f;
  for(int k=s+gl; k<t; k+=16){
    int src = csr_src[k];
    float2 xs = *(const float2*)(xl2 + src*2);
    float h0 = xs.x + xrv.x, h1 = xs.y + xrv.y;
    float l0 = (h0>0.f)? h0 : NEG_SLOPE*h0;
    float l1 = (h1>0.f)? h1 : NEG_SLOPE*h1;
    float ex = __expf(l0*a0 + l1*a1);
    den += ex; n0 += ex*xs.x; n1 += ex*xs.y;
  }
  #pragma unroll
  for(int o=1;o<16;o<<=1){
    den += __shfl_xor(den,o);
    n0  += __shfl_xor(n0,o);
    n1  += __shfl_xor(n1,o);
  }
  if(gl==0){
    float inv = 1.f/(den + EPS);
    out[node*2+0] = n0*inv + b2[0];
    out[node*2+1] = n1*inv + b2[1];
  }
}

extern "C" void kernel_launch(void* const* d_in, const int* in_sizes, int n_in,
                              void* d_out, int out_size, void* d_ws, size_t ws_size,
                              hipStream_t stream){
  const float* x    = (const float*)d_in[0];
  const int*   ei   = (const int*)d_in[1];
  const float* Wl1  = (const float*)d_in[2];
  const float* Wr1  = (const float*)d_in[3];
  const float* att1 = (const float*)d_in[4];
  const float* b1   = (const float*)d_in[5];
  const float* Wl2  = (const float*)d_in[6];
  const float* Wr2  = (const float*)d_in[7];
  const float* att2 = (const float*)d_in[8];
  const float* b2   = (const float*)d_in[9];
  int N = in_sizes[0]/FIN;
  int E = in_sizes[1]/2;
  int Etot = E + N;
  int nscan = (N + SCAN_CHUNK - 1) / SCAN_CHUNK;   // 25 for N=50000 (<=64 required)
  int noct  = (Etot + 7) / 8;
  int ZB = (N + 255) / 256;
  int GDO = (noct + 255) / 256;

  char* w = (char*)d_ws;
  size_t off = 0;
  auto alloc = [&](size_t bytes)->void*{
    void* p = w + off;
    off = (off + bytes + 255) & ~(size_t)255;
    return p;
  };
  float* xr1     = (float*)alloc((size_t)N*H*4);
  unsigned short* xlb = (unsigned short*)alloc((size_t)N*H*2);
  int*   csr_src = (int*)  alloc((size_t)Etot*4);
  int*   rank    = (int*)  alloc((size_t)Etot*4);
  int*   deg     = (int*)  alloc((size_t)N*4);
  int*   rowptr  = (int*)  alloc((size_t)(N+1)*4);
  int*   blocksum= (int*)  alloc((size_t)64*4);
  float* xl2     = (float*)alloc((size_t)N*2*4);
  float* xr2     = (float*)alloc((size_t)N*2*4);
  unsigned short* pWh = (unsigned short*)alloc((size_t)2048*8*2);
  unsigned short* pWe = (unsigned short*)alloc((size_t)2048*8*2);

  k_prep<<<ZB+8, 256, 0, stream>>>(deg, N, ZB, Wl1, Wr1, pWh, pWe);
  k_gemm_mfma<<<(N+63)/64, 256, 0, stream>>>(x, pWh, pWe, xr1, xlb, N);
  k_degree<<<GDO,256,0,stream>>>(ei, E, Etot, deg, rank);
  k_scan_a<<<nscan,256,0,stream>>>(deg, N, rowptr, blocksum);
  k_fill<<<GDO,256,0,stream>>>(ei, E, Etot, rowptr, blocksum, nscan, rank, csr_src);
  k_node1f<<<(N+7)/8, 256, 0, stream>>>(rowptr, blocksum, nscan, csr_src,
                                        xlb, xr1, att1, b1, Wl2, Wr2, xl2, xr2, N);
  k_node2<<<(N+15)/16, 256, 0, stream>>>(rowptr, blocksum, nscan, csr_src,
                                         xl2, xr2, att2, b2, (float*)d_out, N);
}

// Round 16
// 123.123 us; speedup vs baseline: 1.0459x; 1.0459x over previous
//
#include <hip/hip_runtime.h>
#include <math.h>

#define FIN 128
#define H 64
#define FOUT 2
#define NEG_SLOPE 0.2f
#define EPS 1e-16f

#define SCAN_CHUNK 2048   // elements per scan_a block (256 thr * 8)

typedef __attribute__((ext_vector_type(8))) short s8v;   // 8 bf16 (4 VGPR)
typedef __attribute__((ext_vector_type(4))) float f4v;   // MFMA acc

// Preamble: exclusive scan of blocksum[0..nscan) into LDS bs[] (nscan <= 64).
__device__ __forceinline__ void load_bs(const int* __restrict__ blocksum, int nscan,
                                        int* bs, int tid){
  if(tid < 64){
    int v = (tid < nscan)? blocksum[tid] : 0;
    int incl = v;
    #pragma unroll
    for(int o=1;o<64;o<<=1){ int u=__shfl_up(incl,o); if(tid>=o) incl+=u; }
    bs[tid] = incl - v;
  }
  __syncthreads();
}

// K0: fused [zero degs (4 shards)] + [pack W into MFMA fragments, split hi/lo bf16].
__global__ void k_prep(int* __restrict__ degs, int N4, int ZB,
                       const float* __restrict__ Wl, const float* __restrict__ Wr,
                       unsigned short* __restrict__ pWh, unsigned short* __restrict__ pWe){
  int b = blockIdx.x;
  if(b < ZB){
    int i = b*256 + threadIdx.x;
    if(i < N4) degs[i] = 0;
    return;
  }
  int idx = (b - ZB)*256 + threadIdx.x;     // (ct*4+k0)*64 + lane, < 2048
  int lane = idx & 63;
  int ctk  = idx >> 6;
  int k0   = (ctk & 3) * 32;
  int ct   = ctk >> 2;
  int c    = ct*16 + (lane & 15);
  int kb   = k0 + (lane >> 4)*8;
  const float* Wp = (c < 64) ? (Wl + c) : (Wr + (c - 64));
  #pragma unroll
  for(int j=0;j<8;j++){
    float v = Wp[(size_t)(kb + j)*H];
    unsigned u = __float_as_uint(v);
    unsigned short hb = (unsigned short)(u >> 16);
    float hv = __uint_as_float(((unsigned)hb) << 16);
    float ev = v - hv;
    unsigned short eb = (unsigned short)(__float_as_uint(ev) >> 16);
    pWh[(size_t)idx*8 + j] = hb;
    pWe[(size_t)idx*8 + j] = eb;
  }
}

// K1: MFMA GEMM, swapped operands: D = W^T x; float4/ushort4 stores (R15, kept).
__global__ __launch_bounds__(256) void k_gemm_mfma(
    const float* __restrict__ x,
    const unsigned short* __restrict__ pWh, const unsigned short* __restrict__ pWe,
    float* __restrict__ xr, unsigned short* __restrict__ xlb, int N){
  int tid = threadIdx.x;
  int lane = tid & 63, wid = tid >> 6;
  int rowbase = blockIdx.x*64 + wid*16;
  int r = lane & 15, g = lane >> 4;

  int arow = rowbase + r; if(arow > N-1) arow = N-1;
  const float* xrow = x + (size_t)arow*FIN;
  int orow = rowbase + r;

  s8v xh[4], xe[4];
  #pragma unroll
  for(int k0=0;k0<4;k0++){
    float4 va = *(const float4*)(xrow + k0*32 + g*8);
    float4 vb = *(const float4*)(xrow + k0*32 + g*8 + 4);
    float xs_[8] = {va.x,va.y,va.z,va.w,vb.x,vb.y,vb.z,vb.w};
    #pragma unroll
    for(int j=0;j<8;j++){
      unsigned u = __float_as_uint(xs_[j]);
      unsigned short hb = (unsigned short)(u >> 16);
      xh[k0][j] = (short)hb;
      float ev = xs_[j] - __uint_as_float(((unsigned)hb) << 16);
      xe[k0][j] = (short)(unsigned short)(__float_as_uint(ev) >> 16);
    }
  }

  #pragma unroll 2
  for(int ct=0;ct<8;ct++){
    f4v a = (f4v){0.f,0.f,0.f,0.f};
    #pragma unroll
    for(int k0=0;k0<4;k0++){
      size_t boff = ((size_t)(ct*4 + k0)*64 + lane)*8;
      s8v wh = *(const s8v*)(pWh + boff);
      s8v we = *(const s8v*)(pWe + boff);
      a = __builtin_amdgcn_mfma_f32_16x16x32_bf16(wh, xh[k0], a, 0,0,0);
      a = __builtin_amdgcn_mfma_f32_16x16x32_bf16(wh, xe[k0], a, 0,0,0);
      a = __builtin_amdgcn_mfma_f32_16x16x32_bf16(we, xh[k0], a, 0,0,0);
    }
    if(orow < N){
      if(ct < 4){
        ushort4 pk;
        unsigned u0 = __float_as_uint(a[0]);
        unsigned u1 = __float_as_uint(a[1]);
        unsigned u2 = __float_as_uint(a[2]);
        unsigned u3 = __float_as_uint(a[3]);
        pk.x = (unsigned short)((u0 + 0x7FFF + ((u0>>16)&1)) >> 16);
        pk.y = (unsigned short)((u1 + 0x7FFF + ((u1>>16)&1)) >> 16);
        pk.z = (unsigned short)((u2 + 0x7FFF + ((u2>>16)&1)) >> 16);
        pk.w = (unsigned short)((u3 + 0x7FFF + ((u3>>16)&1)) >> 16);
        *(ushort4*)(xlb + (size_t)orow*H + ct*16 + g*4) = pk;
      } else {
        *(float4*)(xr + (size_t)orow*H + (ct-4)*16 + g*4) =
            make_float4(a[0],a[1],a[2],a[3]);
      }
    }
  }
}

// K2: degree + shard-local rank.  4-way sharded counters degs[s][dst], s = j>>1
// for edge slot j of each 8-aligned pack -> same-address atomic chains 17 -> ~4 deep.
__global__ void k_degree(const int* __restrict__ ei, int E, int Etot, int N,
                         int* __restrict__ degs, int* __restrict__ rank){
  int i0 = (blockIdx.x*blockDim.x + threadIdx.x)*8;
  if(i0 >= Etot) return;
  if(i0 + 8 <= E){
    int4 da = *(const int4*)(ei + E + i0);
    int4 db = *(const int4*)(ei + E + i0 + 4);
    int r0 = atomicAdd(&degs[        da.x],1);
    int r1 = atomicAdd(&degs[        da.y],1);
    int r2 = atomicAdd(&degs[  N +   da.z],1);
    int r3 = atomicAdd(&degs[  N +   da.w],1);
    int r4 = atomicAdd(&degs[2*N +   db.x],1);
    int r5 = atomicAdd(&degs[2*N +   db.y],1);
    int r6 = atomicAdd(&degs[3*N +   db.z],1);
    int r7 = atomicAdd(&degs[3*N +   db.w],1);
    *(int4*)(rank + i0)     = make_int4(r0,r1,r2,r3);
    *(int4*)(rank + i0 + 4) = make_int4(r4,r5,r6,r7);
  } else if(i0 >= E && i0 + 8 <= Etot){
    int v = i0 - E;
    int r0 = atomicAdd(&degs[        v+0],1);
    int r1 = atomicAdd(&degs[        v+1],1);
    int r2 = atomicAdd(&degs[  N +   v+2],1);
    int r3 = atomicAdd(&degs[  N +   v+3],1);
    int r4 = atomicAdd(&degs[2*N +   v+4],1);
    int r5 = atomicAdd(&degs[2*N +   v+5],1);
    int r6 = atomicAdd(&degs[3*N +   v+6],1);
    int r7 = atomicAdd(&degs[3*N +   v+7],1);
    *(int4*)(rank + i0)     = make_int4(r0,r1,r2,r3);
    *(int4*)(rank + i0 + 4) = make_int4(r4,r5,r6,r7);
  } else {
    #pragma unroll
    for(int q=0;q<8;q++){
      int i = i0+q; if(i>=Etot) break;
      int dst = (i<E) ? ei[E+i] : (i-E);
      int s = q >> 1;
      rank[i] = atomicAdd(&degs[s*N + dst],1);
    }
  }
}

// K3: per-node total scan (local-exclusive into rowptr + block totals) AND
// in-place shard-exclusive offsets: degs[1][n]=d0, degs[2][n]=d0+d1, degs[3][n]=d0+d1+d2.
__global__ __launch_bounds__(256) void k_scan_a(int* __restrict__ degs, int n,
                                                int* __restrict__ rowptr,
                                                int* __restrict__ blocksum){
  __shared__ int wsum[4];
  int tid = threadIdx.x, lane = tid & 63, wid = tid >> 6;
  int idx = blockIdx.x*SCAN_CHUNK + tid*8;
  int v[8];
  if(idx + 8 <= n){
    int4 a0 = *(const int4*)(degs + idx),         a1 = *(const int4*)(degs + idx + 4);
    int4 b0 = *(const int4*)(degs + n + idx),     b1 = *(const int4*)(degs + n + idx + 4);
    int4 c0 = *(const int4*)(degs + 2*n + idx),   c1 = *(const int4*)(degs + 2*n + idx + 4);
    int4 e0 = *(const int4*)(degs + 3*n + idx),   e1 = *(const int4*)(degs + 3*n + idx + 4);
    *(int4*)(degs + n + idx)     = a0;
    *(int4*)(degs + n + idx + 4) = a1;
    int4 s20 = make_int4(a0.x+b0.x, a0.y+b0.y, a0.z+b0.z, a0.w+b0.w);
    int4 s21 = make_int4(a1.x+b1.x, a1.y+b1.y, a1.z+b1.z, a1.w+b1.w);
    *(int4*)(degs + 2*n + idx)     = s20;
    *(int4*)(degs + 2*n + idx + 4) = s21;
    int4 s30 = make_int4(s20.x+c0.x, s20.y+c0.y, s20.z+c0.z, s20.w+c0.w);
    int4 s31 = make_int4(s21.x+c1.x, s21.y+c1.y, s21.z+c1.z, s21.w+c1.w);
    *(int4*)(degs + 3*n + idx)     = s30;
    *(int4*)(degs + 3*n + idx + 4) = s31;
    v[0]=s30.x+e0.x; v[1]=s30.y+e0.y; v[2]=s30.z+e0.z; v[3]=s30.w+e0.w;
    v[4]=s31.x+e1.x; v[5]=s31.y+e1.y; v[6]=s31.z+e1.z; v[7]=s31.w+e1.w;
  } else {
    #pragma unroll
    for(int i=0;i<8;i++){
      int p = idx+i;
      if(p < n){
        int d0=degs[p], d1=degs[n+p], d2=degs[2*n+p], d3=degs[3*n+p];
        degs[n+p]=d0; degs[2*n+p]=d0+d1; degs[3*n+p]=d0+d1+d2;
        v[i]=d0+d1+d2+d3;
      } else v[i]=0;
    }
  }
  int pre[8]; int st=0;
  #pragma unroll
  for(int i=0;i<8;i++){ pre[i]=st; st+=v[i]; }
  int incl = st;
  #pragma unroll
  for(int o=1;o<64;o<<=1){ int u=__shfl_up(incl,o); if(lane>=o) incl+=u; }
  if(lane==63) wsum[wid]=incl;
  __syncthreads();
  if(tid==0){ int accu=0; for(int i=0;i<4;i++){ int t=wsum[i]; wsum[i]=accu; accu+=t; } }
  __syncthreads();
  int toff = wsum[wid] + incl - st;
  if(idx + 8 <= n){
    int4 o0 = make_int4(toff+pre[0],toff+pre[1],toff+pre[2],toff+pre[3]);
    int4 o1 = make_int4(toff+pre[4],toff+pre[5],toff+pre[6],toff+pre[7]);
    *(int4*)(rowptr+idx)=o0; *(int4*)(rowptr+idx+4)=o1;
  } else {
    #pragma unroll
    for(int i=0;i<8;i++) if(idx+i<n) rowptr[idx+i]=toff+pre[i];
  }
  if(tid==255){
    blocksum[blockIdx.x] = toff + st;
    if(blockIdx.x == gridDim.x-1) rowptr[n] = toff + st;
  }
}

// K4: CSR fill — no atomics; p = rowptr_local[dst] + bs[dst>>11] + shoff[s][dst] + rank[i]
// (shard s = j>>1 per 8-pack slot; shoff for s=0 is 0 by construction, no gather)
__global__ void k_fill(const int* __restrict__ ei, int E, int Etot, int N,
                       const int* __restrict__ rowptr,
                       const int* __restrict__ blocksum, int nscan,
                       const int* __restrict__ degs,
                       const int* __restrict__ rank, int* __restrict__ csr_src){
  __shared__ int bs[64];
  int tid = threadIdx.x;
  load_bs(blocksum, nscan, bs, tid);
  int i0 = (blockIdx.x*blockDim.x + tid)*8;
  if(i0 >= Etot) return;
  if(i0 + 8 <= E){
    int4 sa = *(const int4*)(ei + i0);
    int4 sb = *(const int4*)(ei + i0 + 4);
    int4 da = *(const int4*)(ei + E + i0);
    int4 db = *(const int4*)(ei + E + i0 + 4);
    int4 ra = *(const int4*)(rank + i0);
    int4 rb = *(const int4*)(rank + i0 + 4);
    csr_src[rowptr[da.x] + bs[da.x>>11] +                   ra.x] = sa.x;
    csr_src[rowptr[da.y] + bs[da.y>>11] +                   ra.y] = sa.y;
    csr_src[rowptr[da.z] + bs[da.z>>11] + degs[  N + da.z] + ra.z] = sa.z;
    csr_src[rowptr[da.w] + bs[da.w>>11] + degs[  N + da.w] + ra.w] = sa.w;
    csr_src[rowptr[db.x] + bs[db.x>>11] + degs[2*N + db.x] + rb.x] = sb.x;
    csr_src[rowptr[db.y] + bs[db.y>>11] + degs[2*N + db.y] + rb.y] = sb.y;
    csr_src[rowptr[db.z] + bs[db.z>>11] + degs[3*N + db.z] + rb.z] = sb.z;
    csr_src[rowptr[db.w] + bs[db.w>>11] + degs[3*N + db.w] + rb.w] = sb.w;
  } else if(i0 >= E && i0 + 8 <= Etot){
    int4 ra = *(const int4*)(rank + i0);
    int4 rb = *(const int4*)(rank + i0 + 4);
    int v = i0 - E;
    csr_src[rowptr[v+0] + bs[(v+0)>>11] +                    ra.x] = v+0;
    csr_src[rowptr[v+1] + bs[(v+1)>>11] +                    ra.y] = v+1;
    csr_src[rowptr[v+2] + bs[(v+2)>>11] + degs[  N + (v+2)] + ra.z] = v+2;
    csr_src[rowptr[v+3] + bs[(v+3)>>11] + degs[  N + (v+3)] + ra.w] = v+3;
    csr_src[rowptr[v+4] + bs[(v+4)>>11] + degs[2*N + (v+4)] + rb.x] = v+4;
    csr_src[rowptr[v+5] + bs[(v+5)>>11] + degs[2*N + (v+5)] + rb.y] = v+5;
    csr_src[rowptr[v+6] + bs[(v+6)>>11] + degs[3*N + (v+6)] + rb.z] = v+6;
    csr_src[rowptr[v+7] + bs[(v+7)>>11] + degs[3*N + (v+7)] + rb.w] = v+7;
  } else {
    #pragma unroll
    for(int q=0;q<8;q++){
      int i = i0+q; if(i>=Etot) break;
      int src, dst;
      if(i<E){ src = ei[i]; dst = ei[E+i]; } else { src = i-E; dst = i-E; }
      int s = q >> 1;
      int so = s ? degs[s*N + dst] : 0;
      csr_src[rowptr[dst] + bs[dst>>11] + so + rank[i]] = src;
    }
  }
}

// K5: fused layer-1 (no-max softmax).  16-lane group per node, 4 nodes/wave (R13).
__global__ void k_node1f(const int* __restrict__ rowptr, const int* __restrict__ blocksum,
                         int nscan, const int* __restrict__ csr_src,
                         const unsigned short* __restrict__ xlb, const float* __restrict__ xr,
                         const float* __restrict__ att, const float* __restrict__ b1,
                         const float* __restrict__ Wl2, const float* __restrict__ Wr2,
                         float* __restrict__ xl2, float* __restrict__ xr2, int N){
  __shared__ int bs[64];
  int tid = threadIdx.x;
  load_bs(blocksum, nscan, bs, tid);
  int node = blockIdx.x*16 + (tid>>4);
  int gl = tid & 15;
  if(node >= N) return;
  int f4 = gl*4;
  float4 attv = *(const float4*)(att + f4);
  float4 xrv  = *(const float4*)(xr + (size_t)node*H + f4);
  int s = rowptr[node]   + bs[node>>11];
  int t = rowptr[node+1] + bs[(node+1)>>11];
  float d = 0.f;
  float ax=0.f, ay=0.f, az=0.f, aw=0.f;

  for(int k=s; k<t; k+=8){
    int tl = t - 1;
    int ks[8]; float4 xv[8]; float msk[8];
    #pragma unroll
    for(int j=0;j<8;j++){
      int kj = k + j;
      ks[j] = (kj < t) ? kj : tl;
      msk[j] = (kj < t) ? 1.f : 0.f;
    }
    int ss[8];
    #pragma unroll
    for(int j=0;j<8;j++) ss[j] = csr_src[ks[j]];
    #pragma unroll
    for(int j=0;j<8;j++){
      ushort4 uv = *(const ushort4*)(xlb + (size_t)ss[j]*H + f4);
      xv[j].x = __uint_as_float((unsigned)uv.x << 16);
      xv[j].y = __uint_as_float((unsigned)uv.y << 16);
      xv[j].z = __uint_as_float((unsigned)uv.z << 16);
      xv[j].w = __uint_as_float((unsigned)uv.w << 16);
    }
    #pragma unroll
    for(int j=0;j<8;j++){
      float h0 = xv[j].x + xrv.x, h1 = xv[j].y + xrv.y;
      float h2 = xv[j].z + xrv.z, h3 = xv[j].w + xrv.w;
      float l0 = (h0>0.f)? h0 : NEG_SLOPE*h0;
      float l1 = (h1>0.f)? h1 : NEG_SLOPE*h1;
      float l2 = (h2>0.f)? h2 : NEG_SLOPE*h2;
      float l3 = (h3>0.f)? h3 : NEG_SLOPE*h3;
      float e = l0*attv.x + l1*attv.y + l2*attv.z + l3*attv.w;
      #pragma unroll
      for(int o=1;o<16;o<<=1) e += __shfl_xor(e,o);
      float w = msk[j] * __expf(e);
      d  += w;
      ax += w*xv[j].x; ay += w*xv[j].y; az += w*xv[j].z; aw += w*xv[j].w;
    }
  }

  float inv = 1.f/(d + EPS);
  float4 bv = *(const float4*)(b1 + f4);
  float h0 = ax*inv + bv.x, h1 = ay*inv + bv.y;
  float h2 = az*inv + bv.z, h3 = aw*inv + bv.w;
  float p0 = h0*Wl2[(f4+0)*FOUT+0] + h1*Wl2[(f4+1)*FOUT+0] + h2*Wl2[(f4+2)*FOUT+0] + h3*Wl2[(f4+3)*FOUT+0];
  float p1 = h0*Wl2[(f4+0)*FOUT+1] + h1*Wl2[(f4+1)*FOUT+1] + h2*Wl2[(f4+2)*FOUT+1] + h3*Wl2[(f4+3)*FOUT+1];
  float p2 = h0*Wr2[(f4+0)*FOUT+0] + h1*Wr2[(f4+1)*FOUT+0] + h2*Wr2[(f4+2)*FOUT+0] + h3*Wr2[(f4+3)*FOUT+0];
  float p3 = h0*Wr2[(f4+0)*FOUT+1] + h1*Wr2[(f4+1)*FOUT+1] + h2*Wr2[(f4+2)*FOUT+1] + h3*Wr2[(f4+3)*FOUT+1];
  #pragma unroll
  for(int o=1;o<16;o<<=1){
    p0 += __shfl_xor(p0,o); p1 += __shfl_xor(p1,o);
    p2 += __shfl_xor(p2,o); p3 += __shfl_xor(p3,o);
  }
  if(gl==0){
    *(float2*)(xl2 + node*2) = make_float2(p0,p1);
    *(float2*)(xr2 + node*2) = make_float2(p2,p3);
  }
}

// K6: layer-2 full conv, single pass (no-max), 16-lane group per node
__global__ void k_node2(const int* __restrict__ rowptr, const int* __restrict__ blocksum,
                        int nscan, const int* __restrict__ csr_src,
                        const float* __restrict__ xl2, const float* __restrict__ xr2,
                        const float* __restrict__ att2, const float* __restrict__ b2,
                        float* __restrict__ out, int N){
  __shared__ int bs[64];
  int tid = threadIdx.x;
  load_bs(blocksum, nscan, bs, tid);
  int node = blockIdx.x*16 + (tid>>4);
  int gl = tid & 15;
  if(node >= N) return;
  int s = rowptr[node]   + bs[node>>11];
  int t = rowptr[node+1] + bs[(node+1)>>11];
  float2 xrv = *(const float2*)(xr2 + node*2);
  float a0 = att2[0], a1 = att2[1];
  float den=0.f, n0=0.f, n1=0.f;
  for(int k=s+gl; k<t; k+=16){
    int src = csr_src[k];
    float2 xs = *(const float2*)(xl2 + src*2);
    float h0 = xs.x + xrv.x, h1 = xs.y + xrv.y;
    float l0 = (h0>0.f)? h0 : NEG_SLOPE*h0;
    float l1 = (h1>0.f)? h1 : NEG_SLOPE*h1;
    float ex = __expf(l0*a0 + l1*a1);
    den += ex; n0 += ex*xs.x; n1 += ex*xs.y;
  }
  #pragma unroll
  for(int o=1;o<16;o<<=1){
    den += __shfl_xor(den,o);
    n0  += __shfl_xor(n0,o);
    n1  += __shfl_xor(n1,o);
  }
  if(gl==0){
    float inv = 1.f/(den + EPS);
    out[node*2+0] = n0*inv + b2[0];
    out[node*2+1] = n1*inv + b2[1];
  }
}

extern "C" void kernel_launch(void* const* d_in, const int* in_sizes, int n_in,
                              void* d_out, int out_size, void* d_ws, size_t ws_size,
                              hipStream_t stream){
  const float* x    = (const float*)d_in[0];
  const int*   ei   = (const int*)d_in[1];
  const float* Wl1  = (const float*)d_in[2];
  const float* Wr1  = (const float*)d_in[3];
  const float* att1 = (const float*)d_in[4];
  const float* b1   = (const float*)d_in[5];
  const float* Wl2  = (const float*)d_in[6];
  const float* Wr2  = (const float*)d_in[7];
  const float* att2 = (const float*)d_in[8];
  const float* b2   = (const float*)d_in[9];
  int N = in_sizes[0]/FIN;
  int E = in_sizes[1]/2;
  int Etot = E + N;
  int nscan = (N + SCAN_CHUNK - 1) / SCAN_CHUNK;   // 25 for N=50000 (<=64 required)
  int noct  = (Etot + 7) / 8;
  int ZB = (4*N + 255) / 256;                      // zero 4 shard arrays
  int GDO = (noct + 255) / 256;

  char* w = (char*)d_ws;
  size_t off = 0;
  auto alloc = [&](size_t bytes)->void*{
    void* p = w + off;
    off = (off + bytes + 255) & ~(size_t)255;
    return p;
  };
  float* xr1     = (float*)alloc((size_t)N*H*4);
  unsigned short* xlb = (unsigned short*)alloc((size_t)N*H*2);
  int*   csr_src = (int*)  alloc((size_t)Etot*4);
  int*   rank    = (int*)  alloc((size_t)Etot*4);
  int*   degs    = (int*)  alloc((size_t)4*N*4);   // 4 shards
  int*   rowptr  = (int*)  alloc((size_t)(N+1)*4);
  int*   blocksum= (int*)  alloc((size_t)64*4);
  float* xl2     = (float*)alloc((size_t)N*2*4);
  float* xr2     = (float*)alloc((size_t)N*2*4);
  unsigned short* pWh = (unsigned short*)alloc((size_t)2048*8*2);
  unsigned short* pWe = (unsigned short*)alloc((size_t)2048*8*2);

  k_prep<<<ZB+8, 256, 0, stream>>>(degs, 4*N, ZB, Wl1, Wr1, pWh, pWe);
  k_gemm_mfma<<<(N+63)/64, 256, 0, stream>>>(x, pWh, pWe, xr1, xlb, N);
  k_degree<<<GDO,256,0,stream>>>(ei, E, Etot, N, degs, rank);
  k_scan_a<<<nscan,256,0,stream>>>(degs, N, rowptr, blocksum);
  k_fill<<<GDO,256,0,stream>>>(ei, E, Etot, N, rowptr, blocksum, nscan, degs, rank, csr_src);
  k_node1f<<<(N+15)/16, 256, 0, stream>>>(rowptr, blocksum, nscan, csr_src,
                                          xlb, xr1, att1, b1, Wl2, Wr2, xl2, xr2, N);
  k_node2<<<(N+15)/16, 256, 0, stream>>>(rowptr, blocksum, nscan, csr_src,
                                         xl2, xr2, att2, b2, (float*)d_out, N);
}